// Round 1
// baseline (106.967 us; speedup 1.0000x reference)
//
#include <hip/hip_runtime.h>
#include <math.h>

// Problem constants (from reference): N=4, C=128, H=W=256, G=4, K=5, DIL=1
#define NB   4
#define CC   128
#define HH   256
#define WW   256
#define HWSZ (HH * WW)          // 65536
#define NC   (NB * CC)          // 512
#define GK   20                 // G*K

__device__ __forceinline__ float wave_reduce_sum(float v) {
#pragma unroll
    for (int o = 1; o < 64; o <<= 1) v += __shfl_xor(v, o, 64);
    return v;
}

// ---------------------------------------------------------------------------
// Kernel 1: per-(n,c) plane reductions: rowsum[h], colsum[w], planesum.
// One block per (n,c) plane; each wave reads one full row as float4.
// ---------------------------------------------------------------------------
__global__ __launch_bounds__(256) void k_reduce(const float4* __restrict__ x4,
                                                float* __restrict__ rowsum,
                                                float* __restrict__ colsum,
                                                float* __restrict__ planesum) {
    const int b = blockIdx.x;            // (n,c) index
    const int t = threadIdx.x;
    const int wv = t >> 6;               // wave id 0..3
    const int l = t & 63;                // lane
    const float4* plane = x4 + (size_t)b * (HWSZ / 4);

    float4 cs = make_float4(0.f, 0.f, 0.f, 0.f);
    for (int hb = 0; hb < HH; hb += 4) {
        const int h = hb + wv;
        float4 v = plane[h * (WW / 4) + l];
        cs.x += v.x; cs.y += v.y; cs.z += v.z; cs.w += v.w;
        float r = (v.x + v.y) + (v.z + v.w);
        r = wave_reduce_sum(r);
        if (l == 0) rowsum[b * HH + h] = r;
    }

    __shared__ float colpart[4][WW];
    colpart[wv][4 * l + 0] = cs.x;
    colpart[wv][4 * l + 1] = cs.y;
    colpart[wv][4 * l + 2] = cs.z;
    colpart[wv][4 * l + 3] = cs.w;
    __syncthreads();
    float c = colpart[0][t] + colpart[1][t] + colpart[2][t] + colpart[3][t];
    colsum[b * WW + t] = c;

    // plane sum = sum of all column sums
    float p = wave_reduce_sum(c);
    __shared__ float pr[4];
    if (l == 0) pr[wv] = p;
    __syncthreads();
    if (t == 0) planesum[b] = (pr[0] + pr[1]) + (pr[2] + pr[3]);
}

// ---------------------------------------------------------------------------
// Kernel 2: tiny. f_h = tanh(conv_h @ mean_x); analytic mean(out1);
// f_v = tanh(conv_v @ mean_out1). Single block, 256 threads.
// Reflect-pad boundary corrections for the horizontal conv plane-mean:
//   k=0 (shift -2): S + c1 + c2 - c254 - c255
//   k=1 (shift -1): S + c1 - c255
//   k=2 (shift  0): S
//   k=3 (shift +1): S + c254 - c0
//   k=4 (shift +2): S + c253 + c254 - c0 - c1
// ---------------------------------------------------------------------------
__global__ __launch_bounds__(256) void k_small(const float* __restrict__ colsum,
                                               const float* __restrict__ planesum,
                                               const float* __restrict__ conv_h,
                                               const float* __restrict__ inside_h,
                                               const float* __restrict__ lamb_l_h,
                                               const float* __restrict__ lamb_h_h,
                                               const float* __restrict__ conv_v,
                                               float* __restrict__ f_h_out,
                                               float* __restrict__ f_v_out) {
    __shared__ float meanx[NC];
    __shared__ float fh[NB * GK];
    __shared__ float mo1[NC];
    const int t = threadIdx.x;

    for (int i = t; i < NC; i += 256) meanx[i] = planesum[i] * (1.f / HWSZ);
    __syncthreads();

    if (t < NB * GK) {
        const int n = t / GK, o = t % GK;
        float acc = 0.f;
        for (int c = 0; c < CC; ++c) acc += meanx[n * CC + c] * conv_h[o * CC + c];
        float v = tanhf(acc);
        fh[t] = v;
        f_h_out[t] = v;
    }
    __syncthreads();

    for (int i = t; i < NC; i += 256) {
        const int n = i >> 7, c = i & (CC - 1), g = c >> 5;
        const float* f = &fh[n * GK + g * 5];
        const float S = planesum[i];
        const float* col = colsum + i * WW;
        const float c0 = col[0], c1 = col[1], c2 = col[2];
        const float c253 = col[253], c254 = col[254], c255 = col[255];
        const float s0 = S + c1 + c2 - c254 - c255;
        const float s1 = S + c1 - c255;
        const float s2 = S;
        const float s3 = S + c254 - c0;
        const float s4 = S + c253 + c254 - c0 - c1;
        const float convmean =
            (f[0] * s0 + f[1] * s1 + f[2] * s2 + f[3] * s3 + f[4] * s4) * (1.f / HWSZ);
        const float A = (inside_h[c] + 1.f) * lamb_l_h[c];
        const float B = inside_h[c] * lamb_l_h[c];
        const float Cq = lamb_h_h[c] + 1.f;
        mo1[i] = A * convmean + (Cq - B) * meanx[i];
    }
    __syncthreads();

    if (t < NB * GK) {
        const int n = t / GK, o = t % GK;
        float acc = 0.f;
        for (int c = 0; c < CC; ++c) acc += mo1[n * CC + c] * conv_v[o * CC + c];
        f_v_out[t] = tanhf(acc);
    }
}

// ---------------------------------------------------------------------------
// Kernel 3: fused main pass. Per (n,c,row-tile): rolling 5-row window of
// horizontally-convolved rows (out1), vertical 5-tap combine, gapx_v from
// column means, final gamma*out2 + beta*x.
// ---------------------------------------------------------------------------
#define TH 64  // rows per block tile

__global__ __launch_bounds__(256) void k_main(const float* __restrict__ x,
                                              const float* __restrict__ rowsum,
                                              const float* __restrict__ colsum,
                                              const float* __restrict__ planesum,
                                              const float* __restrict__ f_h,
                                              const float* __restrict__ f_v,
                                              const float* __restrict__ inside_h,
                                              const float* __restrict__ lamb_l_h,
                                              const float* __restrict__ lamb_h_h,
                                              const float* __restrict__ inside_v,
                                              const float* __restrict__ lamb_l_v,
                                              const float* __restrict__ lamb_h_v,
                                              const float* __restrict__ gamma,
                                              const float* __restrict__ beta,
                                              float* __restrict__ out) {
    const int b = blockIdx.x >> 2;        // (n,c)
    const int tile = blockIdx.x & 3;
    const int h0 = tile * TH;
    const int n = b >> 7, c = b & (CC - 1), g = c >> 5;
    const int t = threadIdx.x;

    float fh[5], fv[5];
#pragma unroll
    for (int k = 0; k < 5; ++k) {
        fh[k] = f_h[n * GK + g * 5 + k];
        fv[k] = f_v[n * GK + g * 5 + k];
    }
    const float Ah = (inside_h[c] + 1.f) * lamb_l_h[c];
    const float Bh = inside_h[c] * lamb_l_h[c];
    const float Ch = lamb_h_h[c] + 1.f;
    const float Av = (inside_v[c] + 1.f) * lamb_l_v[c];
    const float Bv = inside_v[c] * lamb_l_v[c];
    const float Cv = lamb_h_v[c] + 1.f;
    const float gm = gamma[c], bt = beta[c];
    const float meanx = planesum[b] * (1.f / HWSZ);

    // gapx_v[w] from column means (reflect-padded 5-tap over colmean)
    __shared__ float lcol[WW + 4];
    lcol[t + 2] = colsum[b * WW + t] * (1.f / HH);
    if (t < 2) lcol[t] = colsum[b * WW + (2 - t)] * (1.f / HH);
    if (t >= WW - 2) lcol[t + 4] = colsum[b * WW + (2 * WW - 4 - t)] * (1.f / HH);
    __syncthreads();
    const float gapxv =
        Ah * (fh[0] * lcol[t] + fh[1] * lcol[t + 1] + fh[2] * lcol[t + 2] +
              fh[3] * lcol[t + 3] + fh[4] * lcol[t + 4]) -
        Bh * meanx + Ch * lcol[t + 2];

    __shared__ float lrow[2][WW + 4];
    const float* plane = x + (size_t)b * HWSZ;
    float r[5], xc[5];
    int idx = 0;
    for (int hs = h0 - 2; hs <= h0 + TH + 1; ++hs, ++idx) {
        const int hr = hs < 0 ? -hs : (hs > HH - 1 ? 2 * HH - 2 - hs : hs);
        float* lb = lrow[idx & 1];
        lb[t + 2] = plane[hr * WW + t];
        if (t < 2) lb[t] = plane[hr * WW + (2 - t)];
        if (t >= WW - 2) lb[t + 4] = plane[hr * WW + (2 * WW - 4 - t)];
        __syncthreads();
        const float conv = fh[0] * lb[t] + fh[1] * lb[t + 1] + fh[2] * lb[t + 2] +
                           fh[3] * lb[t + 3] + fh[4] * lb[t + 4];
        const float xcen = lb[t + 2];
        const float gh = rowsum[b * HH + hr] * (1.f / WW);
        const float r1 = Ah * conv - Bh * gh + Ch * xcen;
        r[0] = r[1]; r[1] = r[2]; r[2] = r[3]; r[3] = r[4]; r[4] = r1;
        xc[0] = xc[1]; xc[1] = xc[2]; xc[2] = xc[3]; xc[3] = xc[4]; xc[4] = xcen;
        if (idx >= 4) {
            const int h = hs - 2;
            const float conv2 = fv[0] * r[0] + fv[1] * r[1] + fv[2] * r[2] +
                                fv[3] * r[3] + fv[4] * r[4];
            const float out2 = Av * conv2 - Bv * gapxv + Cv * r[2];
            out[(size_t)b * HWSZ + h * WW + t] = gm * out2 + bt * xc[2];
        }
    }
}

// ---------------------------------------------------------------------------
extern "C" void kernel_launch(void* const* d_in, const int* in_sizes, int n_in,
                              void* d_out, int out_size, void* d_ws, size_t ws_size,
                              hipStream_t stream) {
    const float* x        = (const float*)d_in[0];
    const float* conv_h   = (const float*)d_in[1];
    const float* inside_h = (const float*)d_in[2];
    const float* lamb_l_h = (const float*)d_in[3];
    const float* lamb_h_h = (const float*)d_in[4];
    const float* conv_v   = (const float*)d_in[5];
    const float* inside_v = (const float*)d_in[6];
    const float* lamb_l_v = (const float*)d_in[7];
    const float* lamb_h_v = (const float*)d_in[8];
    const float* gamma    = (const float*)d_in[9];
    const float* beta     = (const float*)d_in[10];
    float* out = (float*)d_out;

    float* ws = (float*)d_ws;
    float* rowsum   = ws;                 // NC*HH = 131072
    float* colsum   = ws + 131072;        // NC*WW = 131072
    float* planesum = ws + 262144;        // NC = 512
    float* f_h      = ws + 262656;        // 80
    float* f_v      = ws + 262736;        // 80

    k_reduce<<<NC, 256, 0, stream>>>((const float4*)x, rowsum, colsum, planesum);
    k_small<<<1, 256, 0, stream>>>(colsum, planesum, conv_h, inside_h, lamb_l_h,
                                   lamb_h_h, conv_v, f_h, f_v);
    k_main<<<NC * 4, 256, 0, stream>>>(x, rowsum, colsum, planesum, f_h, f_v,
                                       inside_h, lamb_l_h, lamb_h_h,
                                       inside_v, lamb_l_v, lamb_h_v,
                                       gamma, beta, out);
}

// Round 2
// 78.707 us; speedup vs baseline: 1.3591x; 1.3591x over previous
//
#include <hip/hip_runtime.h>
#include <math.h>

// Problem constants (from reference): N=4, C=128, H=W=256, G=4, K=5, DIL=1
#define NB   4
#define CC   128
#define HH   256
#define WW   256
#define HWSZ (HH * WW)          // 65536
#define NC   (NB * CC)          // 512
#define GK   20                 // G*K

__device__ __forceinline__ float wave_reduce_sum(float v) {
#pragma unroll
    for (int o = 1; o < 64; o <<= 1) v += __shfl_xor(v, o, 64);
    return v;
}

// ---------------------------------------------------------------------------
// Kernel 1: per-(n,c) plane reductions: colsum[w], planesum.
// (rowsum dropped — k_main computes row means on the fly via wave reduce)
// One block per (n,c) plane; wave reads 2 rows per iteration (float4).
// ---------------------------------------------------------------------------
__global__ __launch_bounds__(256) void k_reduce(const float4* __restrict__ x4,
                                                float* __restrict__ colsum,
                                                float* __restrict__ planesum) {
    const int b = blockIdx.x;            // (n,c) index
    const int t = threadIdx.x;
    const int wv = t >> 6;               // wave id 0..3
    const int l = t & 63;                // lane
    const float4* plane = x4 + (size_t)b * (HWSZ / 4);

    float4 cs = make_float4(0.f, 0.f, 0.f, 0.f);
    for (int hb = 0; hb < HH; hb += 8) {
        float4 v1 = plane[(hb + wv) * (WW / 4) + l];
        float4 v2 = plane[(hb + 4 + wv) * (WW / 4) + l];
        cs.x += v1.x + v2.x;
        cs.y += v1.y + v2.y;
        cs.z += v1.z + v2.z;
        cs.w += v1.w + v2.w;
    }

    __shared__ float colpart[4][WW];
    colpart[wv][4 * l + 0] = cs.x;
    colpart[wv][4 * l + 1] = cs.y;
    colpart[wv][4 * l + 2] = cs.z;
    colpart[wv][4 * l + 3] = cs.w;
    __syncthreads();
    float c = (colpart[0][t] + colpart[1][t]) + (colpart[2][t] + colpart[3][t]);
    colsum[b * WW + t] = c;

    // plane sum = sum of all column sums
    float p = wave_reduce_sum(c);
    __shared__ float pr[4];
    if (l == 0) pr[wv] = p;
    __syncthreads();
    if (t == 0) planesum[b] = (pr[0] + pr[1]) + (pr[2] + pr[3]);
}

// ---------------------------------------------------------------------------
// Kernel 2: tiny. f_h = tanh(conv_h @ mean_x); analytic mean(out1);
// f_v = tanh(conv_v @ mean_out1). Single block, 256 threads.
// Reflect-pad boundary corrections for the horizontal conv plane-mean:
//   k=0 (shift -2): S + c1 + c2 - c254 - c255
//   k=1 (shift -1): S + c1 - c255
//   k=2 (shift  0): S
//   k=3 (shift +1): S + c254 - c0
//   k=4 (shift +2): S + c253 + c254 - c0 - c1
// ---------------------------------------------------------------------------
__global__ __launch_bounds__(256) void k_small(const float* __restrict__ colsum,
                                               const float* __restrict__ planesum,
                                               const float* __restrict__ conv_h,
                                               const float* __restrict__ inside_h,
                                               const float* __restrict__ lamb_l_h,
                                               const float* __restrict__ lamb_h_h,
                                               const float* __restrict__ conv_v,
                                               float* __restrict__ f_h_out,
                                               float* __restrict__ f_v_out) {
    __shared__ float meanx[NC];
    __shared__ float fh[NB * GK];
    __shared__ float mo1[NC];
    const int t = threadIdx.x;

    for (int i = t; i < NC; i += 256) meanx[i] = planesum[i] * (1.f / HWSZ);
    __syncthreads();

    if (t < NB * GK) {
        const int n = t / GK, o = t % GK;
        float acc = 0.f;
        for (int c = 0; c < CC; ++c) acc += meanx[n * CC + c] * conv_h[o * CC + c];
        float v = tanhf(acc);
        fh[t] = v;
        f_h_out[t] = v;
    }
    __syncthreads();

    for (int i = t; i < NC; i += 256) {
        const int n = i >> 7, c = i & (CC - 1), g = c >> 5;
        const float* f = &fh[n * GK + g * 5];
        const float S = planesum[i];
        const float* col = colsum + i * WW;
        const float c0 = col[0], c1 = col[1], c2 = col[2];
        const float c253 = col[253], c254 = col[254], c255 = col[255];
        const float s0 = S + c1 + c2 - c254 - c255;
        const float s1 = S + c1 - c255;
        const float s2 = S;
        const float s3 = S + c254 - c0;
        const float s4 = S + c253 + c254 - c0 - c1;
        const float convmean =
            (f[0] * s0 + f[1] * s1 + f[2] * s2 + f[3] * s3 + f[4] * s4) * (1.f / HWSZ);
        const float A = (inside_h[c] + 1.f) * lamb_l_h[c];
        const float B = inside_h[c] * lamb_l_h[c];
        const float Cq = lamb_h_h[c] + 1.f;
        mo1[i] = A * convmean + (Cq - B) * meanx[i];
    }
    __syncthreads();

    if (t < NB * GK) {
        const int n = t / GK, o = t % GK;
        float acc = 0.f;
        for (int c = 0; c < CC; ++c) acc += mo1[n * CC + c] * conv_v[o * CC + c];
        f_v_out[t] = tanhf(acc);
    }
}

// ---------------------------------------------------------------------------
// Kernel 3: fused main pass, fully float4-vectorized.
// Wave = one row (64 lanes x float4). Block = 4 rows per iteration.
// Horizontal 5-tap in registers via shuffles (reflect edges = own regs).
// Row mean via wave reduce. hconv rows -> 16-row LDS ring; vertical 5-tap
// reads 5x ds_read_b128. Output lags load by 1 iter so x-center stays in reg.
// One __syncthreads per 4 rows; global load prefetched one iter ahead.
// ---------------------------------------------------------------------------
#define TH 64  // rows per block tile

__global__ __launch_bounds__(256) void k_main(const float* __restrict__ x,
                                              const float* __restrict__ colsum,
                                              const float* __restrict__ planesum,
                                              const float* __restrict__ f_h,
                                              const float* __restrict__ f_v,
                                              const float* __restrict__ inside_h,
                                              const float* __restrict__ lamb_l_h,
                                              const float* __restrict__ lamb_h_h,
                                              const float* __restrict__ inside_v,
                                              const float* __restrict__ lamb_l_v,
                                              const float* __restrict__ lamb_h_v,
                                              const float* __restrict__ gamma,
                                              const float* __restrict__ beta,
                                              float* __restrict__ out) {
    const int b = blockIdx.x >> 2;        // (n,c)
    const int tile = blockIdx.x & 3;
    const int h0 = tile * TH;
    const int n = b >> 7, c = b & (CC - 1), g = c >> 5;
    const int t = threadIdx.x;
    const int wv = t >> 6;                // wave id 0..3
    const int l = t & 63;                 // lane

    float fh[5], fv[5];
#pragma unroll
    for (int k = 0; k < 5; ++k) {
        fh[k] = f_h[n * GK + g * 5 + k];
        fv[k] = f_v[n * GK + g * 5 + k];
    }
    const float Ah = (inside_h[c] + 1.f) * lamb_l_h[c];
    const float Bh = inside_h[c] * lamb_l_h[c];
    const float Ch = lamb_h_h[c] + 1.f;
    const float Av = (inside_v[c] + 1.f) * lamb_l_v[c];
    const float Bv = inside_v[c] * lamb_l_v[c];
    const float Cv = lamb_h_v[c] + 1.f;
    const float gm = gamma[c], bt = beta[c];
    const float meanx = planesum[b] * (1.f / HWSZ);

    // --- gapx_v per column (reflect-padded 5-tap over column means) ---
    __shared__ float lcol[WW + 4];
    lcol[t + 2] = colsum[b * WW + t] * (1.f / HH);
    if (t < 2) lcol[t] = colsum[b * WW + (2 - t)] * (1.f / HH);
    if (t >= WW - 2) lcol[t + 4] = colsum[b * WW + (2 * WW - 4 - t)] * (1.f / HH);
    __syncthreads();
    float gx[4];
    {
        float q[8];
#pragma unroll
        for (int d = 0; d < 8; ++d) q[d] = lcol[4 * l + d];
#pragma unroll
        for (int d = 0; d < 4; ++d) {
            gx[d] = Ah * (fh[0] * q[d] + fh[1] * q[d + 1] + fh[2] * q[d + 2] +
                          fh[3] * q[d + 3] + fh[4] * q[d + 4]) -
                    Bh * meanx + Ch * q[d + 2];
        }
    }

    __shared__ float hring[16][WW];       // hconv ring (16 rows)
    const float* plane = x + (size_t)b * HWSZ;
    float* oplane = out + (size_t)b * HWSZ;

    // load row for super-iter j (wave wv): hs = h0 - 4 + 4j + wv
    auto rowptr = [&](int j) -> const float4* {
        int hs = h0 - 4 + 4 * j + wv;
        int hr = hs < 0 ? -hs : (hs > HH - 1 ? 2 * HH - 2 - hs : hs);
        return (const float4*)&plane[hr * WW + 4 * l];
    };

    float4 vnext = *rowptr(0);
    float4 xprev = make_float4(0.f, 0.f, 0.f, 0.f);

    for (int j = 0; j <= 17; ++j) {
        float4 v;
        if (j <= 16) {
            v = vnext;
            if (j < 16) vnext = *rowptr(j + 1);   // prefetch next row

            // row mean on the fly
            float rsum = (v.x + v.y) + (v.z + v.w);
            rsum = wave_reduce_sum(rsum);
            const float gh = rsum * (1.f / WW);

            // horizontal neighbors via shuffles; reflect edges from own regs
            float xm2 = __shfl_up(v.z, 1);
            float xm1 = __shfl_up(v.w, 1);
            float xp4 = __shfl_down(v.x, 1);
            float xp5 = __shfl_down(v.y, 1);
            if (l == 0)  { xm2 = v.z; xm1 = v.y; }   // x[-2]=x[2], x[-1]=x[1]
            if (l == 63) { xp4 = v.z; xp5 = v.y; }   // x[256]=x[254], x[257]=x[253]

            const float h0v = fh[0] * xm2 + fh[1] * xm1 + fh[2] * v.x + fh[3] * v.y + fh[4] * v.z;
            const float h1v = fh[0] * xm1 + fh[1] * v.x + fh[2] * v.y + fh[3] * v.z + fh[4] * v.w;
            const float h2v = fh[0] * v.x + fh[1] * v.y + fh[2] * v.z + fh[3] * v.w + fh[4] * xp4;
            const float h3v = fh[0] * v.y + fh[1] * v.z + fh[2] * v.w + fh[3] * xp4 + fh[4] * xp5;

            float4 r1;
            r1.x = Ah * h0v - Bh * gh + Ch * v.x;
            r1.y = Ah * h1v - Bh * gh + Ch * v.y;
            r1.z = Ah * h2v - Bh * gh + Ch * v.z;
            r1.w = Ah * h3v - Bh * gh + Ch * v.w;

            const int hs = h0 - 4 + 4 * j + wv;
            *(float4*)&hring[hs & 15][4 * l] = r1;
        }
        __syncthreads();

        if (j >= 2) {
            const int O = h0 - 8 + 4 * j + wv;     // output row (= load row of j-1)
            float ax = 0.f, ay = 0.f, az = 0.f, aw = 0.f;
            float4 rc;
#pragma unroll
            for (int k = 0; k < 5; ++k) {
                int vrow = O + k - 2;
                int vr = vrow < 0 ? -vrow : (vrow > HH - 1 ? 2 * HH - 2 - vrow : vrow);
                float4 hv = *(const float4*)&hring[vr & 15][4 * l];
                ax += fv[k] * hv.x;
                ay += fv[k] * hv.y;
                az += fv[k] * hv.z;
                aw += fv[k] * hv.w;
                if (k == 2) rc = hv;
            }
            float4 res;
            res.x = gm * (Av * ax - Bv * gx[0] + Cv * rc.x) + bt * xprev.x;
            res.y = gm * (Av * ay - Bv * gx[1] + Cv * rc.y) + bt * xprev.y;
            res.z = gm * (Av * az - Bv * gx[2] + Cv * rc.z) + bt * xprev.z;
            res.w = gm * (Av * aw - Bv * gx[3] + Cv * rc.w) + bt * xprev.w;
            *(float4*)&oplane[O * WW + 4 * l] = res;
        }

        if (j <= 16) xprev = v;
    }
}

// ---------------------------------------------------------------------------
extern "C" void kernel_launch(void* const* d_in, const int* in_sizes, int n_in,
                              void* d_out, int out_size, void* d_ws, size_t ws_size,
                              hipStream_t stream) {
    const float* x        = (const float*)d_in[0];
    const float* conv_h   = (const float*)d_in[1];
    const float* inside_h = (const float*)d_in[2];
    const float* lamb_l_h = (const float*)d_in[3];
    const float* lamb_h_h = (const float*)d_in[4];
    const float* conv_v   = (const float*)d_in[5];
    const float* inside_v = (const float*)d_in[6];
    const float* lamb_l_v = (const float*)d_in[7];
    const float* lamb_h_v = (const float*)d_in[8];
    const float* gamma    = (const float*)d_in[9];
    const float* beta     = (const float*)d_in[10];
    float* out = (float*)d_out;

    float* ws = (float*)d_ws;
    float* colsum   = ws;                 // NC*WW = 131072
    float* planesum = ws + 131072;        // NC = 512
    float* f_h      = ws + 131584;        // 80
    float* f_v      = ws + 131664;        // 80

    k_reduce<<<NC, 256, 0, stream>>>((const float4*)x, colsum, planesum);
    k_small<<<1, 256, 0, stream>>>(colsum, planesum, conv_h, inside_h, lamb_l_h,
                                   lamb_h_h, conv_v, f_h, f_v);
    k_main<<<NC * 4, 256, 0, stream>>>(x, colsum, planesum, f_h, f_v,
                                       inside_h, lamb_l_h, lamb_h_h,
                                       inside_v, lamb_l_v, lamb_h_v,
                                       gamma, beta, out);
}